// Round 5
// baseline (150.560 us; speedup 1.0000x reference)
//
#include <hip/hip_runtime.h>
#include <math.h>

// Deformation4D: N=1M gaussians, K_NB=10 neighbors, K_TOTAL=300 control points.
//
// v6: software-pipelined persistent kernel. Evidence so far: five variants
// (43.4-46us) varied LDS bytes, conflicts, VMEM shape, occupancy, wave count
// -- no time response, no pipe >33% busy => latency-bound serialization:
// each wave makes ONE trip through {load -> stall -> gather -> store}.
// v6 gives each thread 4 gaussians (1024 blocks persistent) and issues
// iteration n+1's global loads BEFORE iteration n's gather/FMA chain, so
// VMEM round-trips overlap with LDS+VALU work (2x effective MLP/wave).
//
// Kept: monomial algebra (gather q(16B)+b(16B), rebuild sum(wR) in epilogue),
// 16B-stride de-interleaved LDS table (8 bank-groups, v4-measured 3.15M
// conflicts). Direct idx/weight loads (v5 proved staging is neutral).

struct Accum {
    float W;
    float Mxx, Myy, Mzz, Mxy, Mxz, Myz, Mwx, Mwy, Mwz;
    float qsw, qsx, qsy, qsz;
    float bsx, bsy, bsz;
};

__device__ __forceinline__ void acc_init(Accum& a) {
    a.W = 0.0f;
    a.Mxx = a.Myy = a.Mzz = 0.0f;
    a.Mxy = a.Mxz = a.Myz = 0.0f;
    a.Mwx = a.Mwy = a.Mwz = 0.0f;
    a.qsw = a.qsx = a.qsy = a.qsz = 0.0f;
    a.bsx = a.bsy = a.bsz = 0.0f;
}

__device__ __forceinline__ void acc_neighbor(Accum& a, const float4* __restrict__ tbl,
                                             int K_TOTAL, int cp, float w) {
    float4 q = tbl[cp];             // (w,x,y,z) normalized; 16B stride
    float4 b = tbl[K_TOTAL + cp];   // (bx,by,bz,_)
    float tw = w * q.x, tx = w * q.y, ty = w * q.z, tz = w * q.w;
    a.W += w;
    a.Mxx = fmaf(tx, q.y, a.Mxx);
    a.Myy = fmaf(ty, q.z, a.Myy);
    a.Mzz = fmaf(tz, q.w, a.Mzz);
    a.Mxy = fmaf(tx, q.z, a.Mxy);
    a.Mxz = fmaf(tx, q.w, a.Mxz);
    a.Myz = fmaf(ty, q.w, a.Myz);
    a.Mwx = fmaf(tw, q.y, a.Mwx);
    a.Mwy = fmaf(tw, q.z, a.Mwy);
    a.Mwz = fmaf(tw, q.w, a.Mwz);
    a.qsw += tw; a.qsx += tx; a.qsy += ty; a.qsz += tz;
    a.bsx = fmaf(w, b.x, a.bsx);
    a.bsy = fmaf(w, b.y, a.bsy);
    a.bsz = fmaf(w, b.z, a.bsz);
}

__device__ __forceinline__ void acc_epilogue(const Accum& a,
                                             float mx, float my, float mz,
                                             float4 g,
                                             float* dmx, float* dmy, float* dmz,
                                             float4* oq) {
    float A00 = a.W - 2.0f * (a.Myy + a.Mzz);
    float A01 = 2.0f * (a.Mxy - a.Mwz);
    float A02 = 2.0f * (a.Mxz + a.Mwy);
    float A10 = 2.0f * (a.Mxy + a.Mwz);
    float A11 = a.W - 2.0f * (a.Mxx + a.Mzz);
    float A12 = 2.0f * (a.Myz - a.Mwx);
    float A20 = 2.0f * (a.Mxz - a.Mwy);
    float A21 = 2.0f * (a.Myz + a.Mwx);
    float A22 = a.W - 2.0f * (a.Mxx + a.Myy);

    *dmx = fmaf(A00, mx, fmaf(A01, my, fmaf(A02, mz, a.bsx)));
    *dmy = fmaf(A10, mx, fmaf(A11, my, fmaf(A12, mz, a.bsy)));
    *dmz = fmaf(A20, mx, fmaf(A21, my, fmaf(A22, mz, a.bsz)));

    float n   = sqrtf(a.qsw * a.qsw + a.qsx * a.qsx + a.qsy * a.qsy + a.qsz * a.qsz);
    float inv = 1.0f / fmaxf(n, 1e-8f);
    float bw = a.qsw * inv, bx = a.qsx * inv, by = a.qsy * inv, bz = a.qsz * inv;

    float gw = g.x, gx = g.y, gy = g.z, gz = g.w;
    oq->x = bw * gw - bx * gx - by * gy - bz * gz;
    oq->y = bw * gx + bx * gw + by * gz - bz * gy;
    oq->z = bw * gy - bx * gz + by * gw + bz * gx;
    oq->w = bw * gz + bx * gy - by * gx + bz * gw;
}

__device__ __forceinline__ void build_table(
    const float* __restrict__ ctrl_trans,
    const float* __restrict__ ctrl_rot,
    const float* __restrict__ ctrl_pos,
    float4* __restrict__ tbl, int K_TOTAL)
{
    for (int cp = threadIdx.x; cp < K_TOTAL; cp += blockDim.x) {
        float4 qv = ((const float4*)ctrl_rot)[cp];
        float qw = qv.x, qx = qv.y, qy = qv.z, qz = qv.w;
        float nn  = sqrtf(qw * qw + qx * qx + qy * qy + qz * qz);
        float inv = 1.0f / fmaxf(nn, 1e-8f);
        float w = qw * inv, x = qx * inv, y = qy * inv, z = qz * inv;
        float R00 = 1.0f - 2.0f * (y * y + z * z);
        float R01 = 2.0f * (x * y - w * z);
        float R02 = 2.0f * (x * z + w * y);
        float R10 = 2.0f * (x * y + w * z);
        float R11 = 1.0f - 2.0f * (x * x + z * z);
        float R12 = 2.0f * (y * z - w * x);
        float R20 = 2.0f * (x * z - w * y);
        float R21 = 2.0f * (y * z + w * x);
        float R22 = 1.0f - 2.0f * (x * x + y * y);
        float px = ctrl_pos[cp * 3 + 0];
        float py = ctrl_pos[cp * 3 + 1];
        float pz = ctrl_pos[cp * 3 + 2];
        float tx = ctrl_trans[cp * 3 + 0];
        float ty = ctrl_trans[cp * 3 + 1];
        float tz = ctrl_trans[cp * 3 + 2];
        tbl[cp]           = make_float4(w, x, y, z);
        tbl[K_TOTAL + cp] = make_float4(px + tx - (R00 * px + R01 * py + R02 * pz),
                                        py + ty - (R10 * px + R11 * py + R12 * pz),
                                        pz + tz - (R20 * px + R21 * py + R22 * pz),
                                        0.0f);
    }
}

// Per-gaussian streaming data (held across the pipeline stage).
struct GData {
    int2   i01, i23, i45, i67, i89;
    float2 w01, w23, w45, w67, w89;
    float  mx, my, mz;
    float4 gq;
};

__device__ __forceinline__ void load_g(
    const float* __restrict__ means,
    const float* __restrict__ quats,
    const float* __restrict__ weights,
    const int*   __restrict__ indices,
    long long g, GData& d)
{
    const int2*   ip = (const int2*)(indices + g * 10);   // 40B row, 8B aligned
    const float2* wp = (const float2*)(weights + g * 10);
    d.i01 = ip[0]; d.i23 = ip[1]; d.i45 = ip[2]; d.i67 = ip[3]; d.i89 = ip[4];
    d.w01 = wp[0]; d.w23 = wp[1]; d.w45 = wp[2]; d.w67 = wp[3]; d.w89 = wp[4];
    d.mx = means[g * 3 + 0];
    d.my = means[g * 3 + 1];
    d.mz = means[g * 3 + 2];
    d.gq = ((const float4*)quats)[g];
}

__device__ __forceinline__ void process_g(
    const float4* __restrict__ tbl, int K_TOTAL, const GData& d,
    long long g, float* __restrict__ out_means, float* __restrict__ out_quats)
{
    Accum a; acc_init(a);
    acc_neighbor(a, tbl, K_TOTAL, d.i01.x, d.w01.x);
    acc_neighbor(a, tbl, K_TOTAL, d.i01.y, d.w01.y);
    acc_neighbor(a, tbl, K_TOTAL, d.i23.x, d.w23.x);
    acc_neighbor(a, tbl, K_TOTAL, d.i23.y, d.w23.y);
    acc_neighbor(a, tbl, K_TOTAL, d.i45.x, d.w45.x);
    acc_neighbor(a, tbl, K_TOTAL, d.i45.y, d.w45.y);
    acc_neighbor(a, tbl, K_TOTAL, d.i67.x, d.w67.x);
    acc_neighbor(a, tbl, K_TOTAL, d.i67.y, d.w67.y);
    acc_neighbor(a, tbl, K_TOTAL, d.i89.x, d.w89.x);
    acc_neighbor(a, tbl, K_TOTAL, d.i89.y, d.w89.y);

    float dx, dy, dz;
    float4 oq;
    acc_epilogue(a, d.mx, d.my, d.mz, d.gq, &dx, &dy, &dz, &oq);

    out_means[g * 3 + 0] = dx;
    out_means[g * 3 + 1] = dy;
    out_means[g * 3 + 2] = dz;
    ((float4*)out_quats)[g] = oq;
}

// Fast path: K_NB=10, persistent pipelined loop (prefetch next iteration's
// global loads before the current gather/FMA chain).
__global__ __launch_bounds__(256) void deform_pipe_kernel(
    const float* __restrict__ means,
    const float* __restrict__ quats,
    const float* __restrict__ weights,
    const float* __restrict__ ctrl_trans,
    const float* __restrict__ ctrl_rot,
    const float* __restrict__ ctrl_pos,
    const int*   __restrict__ indices,
    float* __restrict__ out_means,
    float* __restrict__ out_quats,
    int N, int K_TOTAL)
{
    extern __shared__ float4 tbl[];
    build_table(ctrl_trans, ctrl_rot, ctrl_pos, tbl, K_TOTAL);
    __syncthreads();

    const long long stride = (long long)gridDim.x * blockDim.x;
    long long g = (long long)blockIdx.x * blockDim.x + threadIdx.x;
    if (g >= N) return;

    GData cur;
    load_g(means, quats, weights, indices, g, cur);

    for (;;) {
        long long gn = g + stride;
        bool have_next = gn < N;

        GData nxt;
        if (have_next) {
            // issue next iteration's loads NOW; they complete under the
            // current iteration's LDS gather + FMA chain.
            load_g(means, quats, weights, indices, gn, nxt);
        }

        process_g(tbl, K_TOTAL, cur, g, out_means, out_quats);

        if (!have_next) break;
        cur = nxt;
        g = gn;
    }
}

// Generic fallback: runtime K_NB, 1 gaussian per thread.
__global__ __launch_bounds__(256) void deform_generic_kernel(
    const float* __restrict__ means,
    const float* __restrict__ quats,
    const float* __restrict__ weights,
    const float* __restrict__ ctrl_trans,
    const float* __restrict__ ctrl_rot,
    const float* __restrict__ ctrl_pos,
    const int*   __restrict__ indices,
    float* __restrict__ out_means,
    float* __restrict__ out_quats,
    int N, int K_NB, int K_TOTAL)
{
    extern __shared__ float4 tbl[];
    build_table(ctrl_trans, ctrl_rot, ctrl_pos, tbl, K_TOTAL);
    __syncthreads();

    long long i = (long long)blockIdx.x * blockDim.x + threadIdx.x;
    if (i >= N) return;

    const int*   idx_row = indices + i * K_NB;
    const float* w_row   = weights + i * K_NB;
    Accum a; acc_init(a);
    for (int k = 0; k < K_NB; k++)
        acc_neighbor(a, tbl, K_TOTAL, idx_row[k], w_row[k]);

    float mx = means[i * 3 + 0];
    float my = means[i * 3 + 1];
    float mz = means[i * 3 + 2];
    float4 gq = ((const float4*)quats)[i];
    float dx, dy, dz;
    float4 oq;
    acc_epilogue(a, mx, my, mz, gq, &dx, &dy, &dz, &oq);
    out_means[i * 3 + 0] = dx;
    out_means[i * 3 + 1] = dy;
    out_means[i * 3 + 2] = dz;
    ((float4*)out_quats)[i] = oq;
}

extern "C" void kernel_launch(void* const* d_in, const int* in_sizes, int n_in,
                              void* d_out, int out_size, void* d_ws, size_t ws_size,
                              hipStream_t stream) {
    const float* means      = (const float*)d_in[0];
    const float* quats      = (const float*)d_in[1];
    const float* weights    = (const float*)d_in[2];
    const float* ctrl_trans = (const float*)d_in[3];
    const float* ctrl_rot   = (const float*)d_in[4];
    const float* ctrl_pos   = (const float*)d_in[5];
    const int*   indices    = (const int*)d_in[6];

    int N       = in_sizes[0] / 3;
    int K_NB    = in_sizes[2] / N;       // weights is N*K_NB
    int K_TOTAL = in_sizes[3] / 3;       // ctrl_translations is K_TOTAL*3

    float* out_means = (float*)d_out;
    float* out_quats = (float*)d_out + (long long)N * 3;

    int block = 256;
    size_t smem = (size_t)K_TOTAL * 2 * sizeof(float4);

    if (K_NB == 10) {
        // 1024 persistent blocks (4/CU): ~4 gaussians per thread -> 1-deep
        // prefetch hides 3 of 4 VMEM round-trips per wave.
        long long need = ((long long)N + block - 1) / block;
        int grid = (int)(need < 1024 ? need : 1024);
        deform_pipe_kernel<<<grid, block, smem, stream>>>(
            means, quats, weights, ctrl_trans, ctrl_rot, ctrl_pos, indices,
            out_means, out_quats, N, K_TOTAL);
    } else {
        int grid = (int)(((long long)N + block - 1) / block);
        deform_generic_kernel<<<grid, block, smem, stream>>>(
            means, quats, weights, ctrl_trans, ctrl_rot, ctrl_pos, indices,
            out_means, out_quats, N, K_NB, K_TOTAL);
    }
}